// Round 9
// baseline (266.774 us; speedup 1.0000x reference)
//
#include <hip/hip_runtime.h>
#include <stdint.h>

// Problem constants (fixed by setup_inputs)
#define NB 16
#define NTF 4096      // frames T
#define ND 512        // feature dim D
#define NS 8192       // note_size (= 2*T)
#define NCOL 40       // 5 + 10 + 25 output columns
#define ROWSB 64      // rows per block (lane = row)
#define BLOCK 512     // 8 waves
#define CPW 5         // cols per wave
#define NSUB 128      // 512 / 4 : sub-steps of 4 d
#define LGS 65        // Lg row stride

typedef float v4f __attribute__((ext_vector_type(4)));

// W pack (round-5 verbatim, proven): Wp[(u*8 + w)*20 + c*4 + dl] = W[d=u*4+dl][col=w*5+c]
// -> per (wave w, 4-d unit u) slice is 20 contiguous floats (80 B).
extern "C" __global__ void pack_w_kernel(const float* __restrict__ Wg,
                                         const float* __restrict__ Wt,
                                         const float* __restrict__ Wf,
                                         float* __restrict__ Wp)
{
    int o = blockIdx.x * 256 + threadIdx.x;
    if (o >= NCOL * ND) return;
    int s20 = o / 20, r = o % 20;
    int c = r >> 2, dl = r & 3;
    int u = s20 >> 3, w = s20 & 7;
    int d = u * 4 + dl, col = w * 5 + c;
    float v;
    if (col < 5)       v = Wg[d * 5  + col];
    else if (col < 15) v = Wt[d * 10 + (col - 5)];
    else               v = Wf[d * 25 + (col - 15)];
    Wp[o] = v;
}

// No LDS staging, no global_load_lds, no hand-counted waitcnt. All loads are
// compiler-owned so every s_waitcnt is compiler-counted (it tracks its own
// vmcnt precisely). x: per-lane direct global (8 waves share lines -> L1).
// W: uniform-value loads forced onto the VECTOR pipe via an opaque zero
// (prevents s_load scalarization; SMEM has no safe counted wait), pipelined
// one sub-step ahead in source (wA <- wB).
extern "C" __global__ void __launch_bounds__(BLOCK, 6)
hier_main(const float* __restrict__ x,
          const float* __restrict__ bg, const float* __restrict__ bt,
          const float* __restrict__ bf,
          const float* __restrict__ Wp, float* __restrict__ out)
{
    __shared__ float Lg[NCOL * LGS];   // logits [c][row], 10.4 KB (epilogue only)

    const int t    = threadIdx.x;
    const int lane = t & 63;
    const int w    = t >> 6;                            // wave 0..7
    const int row0 = blockIdx.x * ROWSB;
    const int wu   = __builtin_amdgcn_readfirstlane(w);

    // opaque zero: compiler cannot prove the W address is wave-uniform,
    // so W loads stay global_load_dwordx4 (vector pipe, in-order counted vmcnt)
    int z0;
    asm("v_mov_b32 %0, 0" : "=v"(z0));

    const float* xrow = x + (size_t)(row0 + lane) * ND;     // per-lane row base
    const float* wv   = Wp + wu * 20 + z0;                  // wave W stream base

    float acc[CPW];
#pragma unroll
    for (int j = 0; j < CPW; ++j) acc[j] = 0.f;

    v4f wA[CPW], wB[CPW];
    v4f xA, xB;

    // prologue: sub 0 operands
#pragma unroll
    for (int j = 0; j < CPW; ++j) wA[j] = *(const v4f*)(wv + j * 4);
    xA = *(const v4f*)(xrow);

    for (int it = 0; it < NSUB / 8; ++it) {
        // raw barrier (no drain): keeps the 8 waves loosely in phase so their
        // shared x lines stay L1/L2-resident; no waitcnt semantics needed.
        __builtin_amdgcn_s_barrier();
#pragma unroll
        for (int k = 0; k < 8; ++k) {
            const int s  = it * 8 + k;
            int sn = s + 1; if (sn > NSUB - 1) sn = NSUB - 1;   // tail: benign reload
            // prefetch next sub's operands (compiler schedules, counts, waits)
#pragma unroll
            for (int j = 0; j < CPW; ++j)
                wB[j] = *(const v4f*)(wv + (size_t)sn * 160 + j * 4);
            xB = *(const v4f*)(xrow + (size_t)sn * 4);
            // 20 FMAs on current operands
#pragma unroll
            for (int j = 0; j < CPW; ++j) {
                float a = acc[j];
                a = fmaf(xA.x, wA[j].x, a);
                a = fmaf(xA.y, wA[j].y, a);
                a = fmaf(xA.z, wA[j].z, a);
                a = fmaf(xA.w, wA[j].w, a);
                acc[j] = a;
            }
#pragma unroll
            for (int j = 0; j < CPW; ++j) wA[j] = wB[j];    // SSA rename, no moves
            xA = xB;
        }
    }

    // ---- share logits: Lg[col][row] (lane-consecutive: conflict-free) ----
#pragma unroll
    for (int j = 0; j < CPW; ++j) Lg[(wu * CPW + j) * LGS + lane] = acc[j];
    __syncthreads();

    // ---- phase A: per-row bias + hierarchical argmax chain (wave 0) ----
    if (t < ROWSB) {
        constexpr int TOWN[10] = {0,1,2,2,2,3,3,3,4,4};
        constexpr int FOWN[25] = {0,1,2,2,2,3,3,3,3,3,3,3,3,4,9,6,8,5,7,1,3,3,3,9,3};
        const int r = t;
        float gl[5]; int gp = 0; float gbest = -INFINITY;
#pragma unroll
        for (int c = 0; c < 5; ++c) {
            float v = Lg[c * LGS + r] + bg[c];
            gl[c] = v;
            if (v > gbest) { gbest = v; gp = c; }   // strict > == jnp.argmax first-max
        }
        float tl[10]; int tp = 0; float tbest = -INFINITY;
#pragma unroll
        for (int k = 0; k < 10; ++k) {
            float v = (Lg[(5 + k) * LGS + r] + bt[k]) * ((TOWN[k] == gp) ? 1.f : 0.f);
            tl[k] = v;
            if (v > tbest) { tbest = v; tp = k; }
        }
#pragma unroll
        for (int c = 0; c < 5; ++c)  Lg[c * LGS + r] = gl[c];
#pragma unroll
        for (int k = 0; k < 10; ++k) Lg[(5 + k) * LGS + r] = tl[k];
#pragma unroll
        for (int f = 0; f < 25; ++f) {
            float v = (Lg[(15 + f) * LGS + r] + bf[f]) * ((FOWN[f] == tp) ? 1.f : 0.f);
            Lg[(15 + f) * LGS + r] = v;
        }
    }
    __syncthreads();

    // ---- phase B: FULLY COALESCED linear stores (consecutive t -> consecutive
    // floats): each 128B line written back-to-back by one wave ----
    const int b   = row0 >> 12;
    const int tt0 = row0 & (NTF - 1);

    {   // group_up [B][S][5]: 128 frames x 5 = 640 floats
        float* og = out + ((size_t)b * NS + 2 * (size_t)tt0) * 5;
        for (int i = t; i < 640; i += BLOCK) {
            int s = i / 5, c = i - s * 5;
            og[i] = Lg[c * LGS + (s >> 1)];
        }
    }
    {   // tech_up [B][S][10]: 1280 floats
        float* ot = out + (size_t)NB * NS * 5 + ((size_t)b * NS + 2 * (size_t)tt0) * 10;
        for (int i = t; i < 1280; i += BLOCK) {
            int s = i / 10, c = i - s * 10;
            ot[i] = Lg[(5 + c) * LGS + (s >> 1)];
        }
    }
    {   // final_up [B][S][25]: 3200 floats
        float* of = out + (size_t)NB * NS * 15 + ((size_t)b * NS + 2 * (size_t)tt0) * 25;
        for (int i = t; i < 3200; i += BLOCK) {
            int s = i / 25, c = i - s * 25;
            of[i] = Lg[(15 + c) * LGS + (s >> 1)];
        }
    }
    {   // frame_level_final_tech_logits [B][T][25]: 1600 floats
        float* ofr = out + (size_t)NB * NS * 40 + ((size_t)b * NTF + tt0) * 25;
        for (int i = t; i < 1600; i += BLOCK) {
            int s = i / 25, c = i - s * 25;
            ofr[i] = Lg[(15 + c) * LGS + s];
        }
    }
}

extern "C" void kernel_launch(void* const* d_in, const int* in_sizes, int n_in,
                              void* d_out, int out_size, void* d_ws, size_t ws_size,
                              hipStream_t stream)
{
    const float* x  = (const float*)d_in[0];
    const float* Wg = (const float*)d_in[1];
    const float* bg = (const float*)d_in[2];
    const float* Wt = (const float*)d_in[3];
    const float* bt = (const float*)d_in[4];
    const float* Wf = (const float*)d_in[5];
    const float* bf = (const float*)d_in[6];
    float* Wp   = (float*)d_ws;          // 40*512*4 = 80 KB packed weights
    float* outp = (float*)d_out;

    hipLaunchKernelGGL(pack_w_kernel, dim3((NCOL * ND + 255) / 256), dim3(256), 0, stream,
                       Wg, Wt, Wf, Wp);
    hipLaunchKernelGGL(hier_main, dim3((NB * NTF) / ROWSB), dim3(BLOCK), 0, stream,
                       x, bg, bt, bf, Wp, outp);
}

// Round 10
// 81.628 us; speedup vs baseline: 3.2682x; 3.2682x over previous
//
#include <hip/hip_runtime.h>
#include <stdint.h>

// Problem constants (fixed by setup_inputs)
#define NB 16
#define NTF 4096      // frames T
#define ND 512        // feature dim D
#define NS 8192       // note_size (= 2*T)
#define NCOL 40       // 5 + 10 + 25 output columns
#define ROWSB 256     // rows per block (R=4 per lane)
#define BLOCK 512     // 8 waves
#define CPW 5         // cols per wave
#define CD 32         // chunk depth (floats of d)
#define NCH 16        // 512 / 32
#define LGS 260       // Lg row stride (256 + 4)

typedef float v4f __attribute__((ext_vector_type(4)));

// W pack: Wpk[w*2560 + j*64 + l] = W[d = 8*l + (j&7)][col = w*5 + (j>>3)]
// -> main kernel loads wreg[j] = Wpk[wu*2560 + j*64 + lane]: 40 coalesced dwords;
//    lane l then holds W[col][8l..8l+7] for its wave's 5 cols.
extern "C" __global__ void pack_w_kernel(const float* __restrict__ Wg,
                                         const float* __restrict__ Wt,
                                         const float* __restrict__ Wf,
                                         float* __restrict__ Wpk)
{
    int o = blockIdx.x * 256 + threadIdx.x;
    if (o >= NCOL * ND) return;
    int w = o / 2560, rem = o % 2560;
    int j = rem >> 6, l = rem & 63;
    int d = 8 * l + (j & 7), col = w * 5 + (j >> 3);
    float v;
    if (col < 5)       v = Wg[d * 5  + col];
    else if (col < 15) v = Wt[d * 10 + (col - 5)];
    else               v = Wf[d * 25 + (col - 15)];
    Wpk[o] = v;
}

#define GLDS(gp, lp) __builtin_amdgcn_global_load_lds( \
    (const __attribute__((address_space(1))) unsigned int*)(gp), \
    (__attribute__((address_space(3))) unsigned int*)(lp), 16, 0, 0)

static __device__ __forceinline__ float rdlane(float v, int lane_sel) {
    return __builtin_bit_cast(float,
        __builtin_amdgcn_readlane(__builtin_bit_cast(int, v), lane_sel));
}

// 8 waves x 5 cols; lane handles rows {lane, lane+64, lane+128, lane+192} (R=4).
// W: register-resident per wave (40 VGPR/lane), broadcast via v_readlane (VALU)
//    -> zero W memory traffic in the loop, no waitcnt hazards.
// x: chunk (256 rows x 32 d = 32KB) triple-buffered in LDS; GLDS staging is
//    LINE-COALESCED (each GLDS = 8 rows x one full 128B line) with the XOR
//    swizzle folded into the source quad index (stays within the line).
extern "C" __global__ void __launch_bounds__(BLOCK, 2)
hier_main(const float* __restrict__ x,
          const float* __restrict__ bg, const float* __restrict__ bt,
          const float* __restrict__ bf,
          const float* __restrict__ Wpk, float* __restrict__ out)
{
    __shared__ __align__(16) char smem[3 * 32768];   // 96 KB: 3 x-chunk bufs; Lg unions in
    float* Lg = (float*)smem;                         // [40][LGS], used after final barrier

    const int t    = threadIdx.x;
    const int lane = t & 63;
    const int w    = t >> 6;                          // wave 0..7
    const int wu   = __builtin_amdgcn_readfirstlane(w);
    const int row0 = blockIdx.x * ROWSB;

    // ---- one-time W load into per-lane registers (40 VGPR), coalesced ----
    float wreg[40];
#pragma unroll
    for (int j = 0; j < 40; ++j)
        wreg[j] = Wpk[wu * 2560 + j * 64 + lane];

    // x staging: wave w issues GLDS i = w, w+8, w+16, w+24 (4 of 32 per chunk).
    // GLDS i covers rows [i*8, i*8+8); lane l -> row i*8 + (l>>3), phys quad l&7,
    // which stores logical quad (l&7) ^ (row&7)  [row&7 == l>>3 here].
    auto stageX = [&](int ch_) {
        char* dst = smem + (size_t)(ch_ % 3) * 32768;
#pragma unroll
        for (int k = 0; k < 4; ++k) {
            const int i = w + k * 8;                  // 0..31
            const int r = i * 8 + (lane >> 3);        // row within block
            const int q = (lane & 7) ^ (r & 7);       // logical d-quad at this slot
            const float* gp = x + (size_t)(row0 + r) * ND + ch_ * CD + q * 4;
            GLDS(gp, dst + (size_t)i * 1024);
        }
    };

    // drain W loads so the GLDS vmcnt counting below is exact
    asm volatile("s_waitcnt vmcnt(0)" ::: "memory");
    stageX(0);
    stageX(1);

    float acc[4][CPW];
#pragma unroll
    for (int r = 0; r < 4; ++r)
#pragma unroll
        for (int c = 0; c < CPW; ++c) acc[r][c] = 0.f;

#pragma unroll 1
    for (int ch = 0; ch < NCH; ++ch) {
        // own stage(ch) landed; stage(ch+1)'s 4 stay in flight
        if (ch < NCH - 1) asm volatile("s_waitcnt vmcnt(4)" ::: "memory");
        else              asm volatile("s_waitcnt vmcnt(0)" ::: "memory");
        __builtin_amdgcn_s_barrier();                 // all waves' slices visible
        __builtin_amdgcn_sched_barrier(0);
        if (ch < NCH - 2) stageX(ch + 2);             // overwrites buf read at ch-1 (past barrier)
        __builtin_amdgcn_sched_barrier(0);

        const float* xbuf = (const float*)(smem + (size_t)(ch % 3) * 32768);
        const int key = lane & 7;

#pragma unroll
        for (int p = 0; p < 4; ++p) {                 // 4 pairs of 4-d subs (8 d each)
            // x: 4 rows x 2 swizzled quads (standard min-cost b128 pattern)
            v4f xlo[4], xhi[4];
#pragma unroll
            for (int r = 0; r < 4; ++r) {
                const int row = r * 64 + lane;
                xlo[r] = *(const v4f*)(xbuf + (size_t)row * CD + (size_t)(((2*p)   ^ key) * 4));
                xhi[r] = *(const v4f*)(xbuf + (size_t)row * CD + (size_t)(((2*p+1) ^ key) * 4));
            }
            const int lsel = ch * 4 + p;              // uniform readlane selector
#pragma unroll
            for (int c = 0; c < CPW; ++c) {
#pragma unroll
                for (int e = 0; e < 8; ++e) {
                    const float wv = rdlane(wreg[c * 8 + e], lsel);
#pragma unroll
                    for (int r = 0; r < 4; ++r) {
                        const float xv = (e < 4) ? xlo[r][e] : xhi[r][e - 4];
                        acc[r][c] = fmaf(xv, wv, acc[r][c]);
                    }
                }
            }
        }
    }

    // ---- all reads of x bufs done; overlay Lg ----
    __syncthreads();
#pragma unroll
    for (int c = 0; c < CPW; ++c)
#pragma unroll
        for (int r = 0; r < 4; ++r)
            Lg[(wu * CPW + c) * LGS + r * 64 + lane] = acc[r][c];
    __syncthreads();

    // ---- phase A: per-row bias + hierarchical argmax chain (threads 0..255) ----
    if (t < ROWSB) {
        constexpr int TOWN[10] = {0,1,2,2,2,3,3,3,4,4};
        constexpr int FOWN[25] = {0,1,2,2,2,3,3,3,3,3,3,3,3,4,9,6,8,5,7,1,3,3,3,9,3};
        const int r = t;
        float gl[5]; int gp = 0; float gbest = -INFINITY;
#pragma unroll
        for (int c = 0; c < 5; ++c) {
            float v = Lg[c * LGS + r] + bg[c];
            gl[c] = v;
            if (v > gbest) { gbest = v; gp = c; }   // strict > == jnp.argmax first-max
        }
        float tl[10]; int tp = 0; float tbest = -INFINITY;
#pragma unroll
        for (int k = 0; k < 10; ++k) {
            float v = (Lg[(5 + k) * LGS + r] + bt[k]) * ((TOWN[k] == gp) ? 1.f : 0.f);
            tl[k] = v;
            if (v > tbest) { tbest = v; tp = k; }
        }
#pragma unroll
        for (int c = 0; c < 5; ++c)  Lg[c * LGS + r] = gl[c];
#pragma unroll
        for (int k = 0; k < 10; ++k) Lg[(5 + k) * LGS + r] = tl[k];
#pragma unroll
        for (int f = 0; f < 25; ++f) {
            float v = (Lg[(15 + f) * LGS + r] + bf[f]) * ((FOWN[f] == tp) ? 1.f : 0.f);
            Lg[(15 + f) * LGS + r] = v;
        }
    }
    __syncthreads();

    // ---- phase B: FULLY COALESCED linear stores ----
    const int b   = row0 >> 12;
    const int tt0 = row0 & (NTF - 1);

    {   // group_up [B][S][5]: 512 frames x 5 = 2560 floats
        float* og = out + ((size_t)b * NS + 2 * (size_t)tt0) * 5;
        for (int i = t; i < 2560; i += BLOCK) {
            int s = i / 5, c = i - s * 5;
            og[i] = Lg[c * LGS + (s >> 1)];
        }
    }
    {   // tech_up [B][S][10]: 5120 floats
        float* ot = out + (size_t)NB * NS * 5 + ((size_t)b * NS + 2 * (size_t)tt0) * 10;
        for (int i = t; i < 5120; i += BLOCK) {
            int s = i / 10, c = i - s * 10;
            ot[i] = Lg[(5 + c) * LGS + (s >> 1)];
        }
    }
    {   // final_up [B][S][25]: 12800 floats
        float* of = out + (size_t)NB * NS * 15 + ((size_t)b * NS + 2 * (size_t)tt0) * 25;
        for (int i = t; i < 12800; i += BLOCK) {
            int s = i / 25, c = i - s * 25;
            of[i] = Lg[(15 + c) * LGS + (s >> 1)];
        }
    }
    {   // frame_level_final_tech_logits [B][T][25]: 6400 floats
        float* ofr = out + (size_t)NB * NS * 40 + ((size_t)b * NTF + tt0) * 25;
        for (int i = t; i < 6400; i += BLOCK) {
            int s = i / 25, c = i - s * 25;
            ofr[i] = Lg[(15 + c) * LGS + s];
        }
    }
}

extern "C" void kernel_launch(void* const* d_in, const int* in_sizes, int n_in,
                              void* d_out, int out_size, void* d_ws, size_t ws_size,
                              hipStream_t stream)
{
    const float* x  = (const float*)d_in[0];
    const float* Wg = (const float*)d_in[1];
    const float* bg = (const float*)d_in[2];
    const float* Wt = (const float*)d_in[3];
    const float* bt = (const float*)d_in[4];
    const float* Wf = (const float*)d_in[5];
    const float* bf = (const float*)d_in[6];
    float* Wpk  = (float*)d_ws;          // 40*512*4 = 80 KB packed weights
    float* outp = (float*)d_out;

    hipLaunchKernelGGL(pack_w_kernel, dim3((NCOL * ND + 255) / 256), dim3(256), 0, stream,
                       Wg, Wt, Wf, Wpk);
    hipLaunchKernelGGL(hier_main, dim3((NB * NTF) / ROWSB), dim3(BLOCK), 0, stream,
                       x, bg, bt, bf, Wpk, outp);
}